// Round 6
// baseline (981.942 us; speedup 1.0000x reference)
//
#include <hip/hip_runtime.h>
#include <math.h>

// Problem constants
#define NL    1568          // left nodes (B*P)
#define NTOT  3136          // total nodes
#define DD    768           // feature dim
#define NH    12            // heads
#define DHD   64            // head dim
#define WPR   49            // mask words per row (1568/32)
#define MAXDEG 64           // neighbor-list capacity
#define LOG2F_ 0.69314718055994530942f

typedef _Float16 h8 __attribute__((ext_vector_type(8)));
typedef _Float16 h4 __attribute__((ext_vector_type(4)));
typedef float f32x4 __attribute__((ext_vector_type(4)));
#define MFMA16(a, b, c) __builtin_amdgcn_mfma_f32_16x16x32_f16(a, b, c, 0, 0, 0)

__device__ __forceinline__ float leaky(float x) { return x > 0.f ? x : 0.2f * x; }

// ---------------------------------------------------------------- init h = concat(l,r)
__global__ void init_h(const float* __restrict__ lf, const float* __restrict__ rf, float* __restrict__ h) {
  int idx = blockIdx.x * 256 + threadIdx.x;
  if (idx >= NTOT * DD) return;
  h[idx] = (idx < NL * DD) ? lf[idx] : rf[idx - NL * DD];
}

// ---------------------------------------------------------------- h (fp32) -> hi + lo*2^-11 fp16 planes
__global__ void conv_h(const float* __restrict__ x, _Float16* __restrict__ hi, _Float16* __restrict__ lo) {
  int idx = blockIdx.x * 256 + threadIdx.x;
  if (idx >= NTOT * DD / 4) return;
  float4 v = reinterpret_cast<const float4*>(x)[idx];
  _Float16 a0 = (_Float16)v.x, a1 = (_Float16)v.y, a2 = (_Float16)v.z, a3 = (_Float16)v.w;
  h4 hv = {a0, a1, a2, a3};
  h4 lv = {(_Float16)((v.x - (float)a0) * 2048.f), (_Float16)((v.y - (float)a1) * 2048.f),
           (_Float16)((v.z - (float)a2) * 2048.f), (_Float16)((v.w - (float)a3) * 2048.f)};
  reinterpret_cast<h4*>(hi)[idx] = hv;
  reinterpret_cast<h4*>(lo)[idx] = lv;
}

// ---------------------------------------------------------------- W[i][k][n] -> Wt[i][n][k] hi/lo fp16
__global__ __launch_bounds__(256) void transp_W(const float* __restrict__ W, _Float16* __restrict__ Wthi,
                                                _Float16* __restrict__ Wtlo) {
  __shared__ float tile[32][33];
  int kt = blockIdx.x * 32, nt = blockIdx.y * 32, i = blockIdx.z;
  int tx = threadIdx.x & 31, ty = threadIdx.x >> 5;
  const float* Wp = W + ((size_t)i * DD + kt) * DD + nt;
  #pragma unroll
  for (int p = 0; p < 4; ++p) tile[ty + p * 8][tx] = Wp[(size_t)(ty + p * 8) * DD + tx];
  __syncthreads();
  _Float16* oh = Wthi + ((size_t)i * DD + nt) * DD + kt;
  _Float16* ol = Wtlo + ((size_t)i * DD + nt) * DD + kt;
  #pragma unroll
  for (int p = 0; p < 4; ++p) {
    int nn = ty + p * 8;
    float v = tile[tx][nn];
    _Float16 vh = (_Float16)v;
    oh[(size_t)nn * DD + tx] = vh;
    ol[(size_t)nn * DD + tx] = (_Float16)((v - (float)vh) * 2048.f);
  }
}

// ---------------------------------------------------------------- row norms (fp32 h)
__global__ __launch_bounds__(256) void norms_kernel(const float* __restrict__ h, float* __restrict__ norms) {
  int n = blockIdx.x;
  __shared__ float red[256];
  float s = 0.f;
  for (int d = threadIdx.x; d < DD; d += 256) {
    float v = h[(size_t)n * DD + d];
    s = fmaf(v, v, s);
  }
  red[threadIdx.x] = s;
  __syncthreads();
  for (int o = 128; o > 0; o >>= 1) {
    if (threadIdx.x < o) red[threadIdx.x] += red[threadIdx.x + o];
    __syncthreads();
  }
  if (threadIdx.x == 0) norms[n] = sqrtf(red[0]);
}

// ---------------------------------------------------------------- fused MFMA GEMM: z = h @ W, + el/er + left/non-root h-write
// grid (49, 12): by == head. 256 thr = 4 waves, wave = 16 rows x 64 cols.
__global__ __launch_bounds__(256) void gemm_mfma(const _Float16* __restrict__ Ahi, const _Float16* __restrict__ Alo,
                                                 const _Float16* __restrict__ Bhi, const _Float16* __restrict__ Blo,
                                                 const float* __restrict__ a_s, const float* __restrict__ a_d,
                                                 const float* __restrict__ bias, float* __restrict__ C,
                                                 float* __restrict__ el, float* __restrict__ er,
                                                 float* __restrict__ hout, int do_elu, int mode) {
  int t = threadIdx.x;
  int ln = t & 63, wv = t >> 6;
  int m0 = blockIdx.x * 64 + wv * 16;
  int n0 = blockIdx.y * 64;
  int fr = ln & 15, kg = ln >> 4;
  const _Float16* ah_p = Ahi + (size_t)(m0 + fr) * DD + kg * 8;
  const _Float16* al_p = Alo + (size_t)(m0 + fr) * DD + kg * 8;
  const _Float16* bh_p = Bhi + (size_t)(n0 + fr) * DD + kg * 8;
  const _Float16* bl_p = Blo + (size_t)(n0 + fr) * DD + kg * 8;
  f32x4 zero = {0.f, 0.f, 0.f, 0.f};
  f32x4 acc1[4], acc2[4];
  #pragma unroll
  for (int cg = 0; cg < 4; ++cg) { acc1[cg] = zero; acc2[cg] = zero; }
  for (int kb = 0; kb < DD; kb += 32) {
    h8 ah = *reinterpret_cast<const h8*>(ah_p + kb);
    h8 al = *reinterpret_cast<const h8*>(al_p + kb);
    #pragma unroll
    for (int cg = 0; cg < 4; ++cg) {
      h8 bh = *reinterpret_cast<const h8*>(bh_p + (size_t)cg * 16 * DD + kb);
      h8 bl = *reinterpret_cast<const h8*>(bl_p + (size_t)cg * 16 * DD + kb);
      acc1[cg] = MFMA16(ah, bh, acc1[cg]);
      acc2[cg] = MFMA16(ah, bl, acc2[cg]);
      acc2[cg] = MFMA16(al, bh, acc2[cg]);
    }
  }
  int head = blockIdx.y;
  int orow = m0 + kg * 4;
  float zv[4][4];
  #pragma unroll
  for (int cg = 0; cg < 4; ++cg)
    #pragma unroll
    for (int i = 0; i < 4; ++i) zv[cg][i] = acc1[cg][i] + acc2[cg][i] * (1.f / 2048.f);
  // store z + fused h-write
  #pragma unroll
  for (int i = 0; i < 4; ++i) {
    int r = orow + i;
    bool wh = (mode == 0) ? (r < NL) : (r % 196 != 0);
    #pragma unroll
    for (int cg = 0; cg < 4; ++cg) {
      int c = n0 + cg * 16 + fr;
      float z = zv[cg][i];
      C[(size_t)r * DD + c] = z;
      if (wh) {
        float o = z + bias[c];
        if (do_elu) o = o > 0.f ? o : expm1f(o);
        hout[(size_t)r * DD + c] = o;
      }
    }
  }
  // fused el/er: this block owns head == by, cols cg*16+fr
  float asv[4], adv[4];
  #pragma unroll
  for (int cg = 0; cg < 4; ++cg) {
    asv[cg] = a_s[head * DHD + cg * 16 + fr];
    adv[cg] = a_d[head * DHD + cg * 16 + fr];
  }
  #pragma unroll
  for (int i = 0; i < 4; ++i) {
    float s1 = 0.f, s2 = 0.f;
    #pragma unroll
    for (int cg = 0; cg < 4; ++cg) {
      s1 = fmaf(zv[cg][i], asv[cg], s1);
      s2 = fmaf(zv[cg][i], adv[cg], s2);
    }
    #pragma unroll
    for (int o = 1; o < 16; o <<= 1) {
      s1 += __shfl_xor(s1, o);
      s2 += __shfl_xor(s2, o);
    }
    if (fr == 0) {
      el[(size_t)(orow + i) * NH + head] = s1;
      er[(size_t)(orow + i) * NH + head] = s2;
    }
  }
}

// ---------------------------------------------------------------- mask via MFMA (NT): h_r . h_l > 0.1 |r||l|
// grid (25, 25), tile 64r x 64l
__global__ __launch_bounds__(256) void mask_mfma(const _Float16* __restrict__ Hhi, const _Float16* __restrict__ Hlo,
                                                 const float* __restrict__ norms, unsigned* __restrict__ mask) {
  __shared__ unsigned mw[64][2];
  int t = threadIdx.x;
  int ln = t & 63, wv = t >> 6;
  int r0 = blockIdx.x * 64, n0 = blockIdx.y * 64;
  int fr = ln & 15, kg = ln >> 4;
  int ar = r0 + wv * 16 + fr; if (ar >= NL) ar = NL - 1;
  const _Float16* ah_p = Hhi + (size_t)(NL + ar) * DD + kg * 8;
  const _Float16* al_p = Hlo + (size_t)(NL + ar) * DD + kg * 8;
  int lb[4];
  #pragma unroll
  for (int cg = 0; cg < 4; ++cg) { int l = n0 + cg * 16 + fr; lb[cg] = l < NL ? l : NL - 1; }
  f32x4 zero = {0.f, 0.f, 0.f, 0.f};
  f32x4 acc1[4], acc2[4];
  #pragma unroll
  for (int cg = 0; cg < 4; ++cg) { acc1[cg] = zero; acc2[cg] = zero; }
  if (t < 128) mw[t >> 1][t & 1] = 0u;
  for (int kb = 0; kb < DD; kb += 32) {
    h8 ah = *reinterpret_cast<const h8*>(ah_p + kb);
    h8 al = *reinterpret_cast<const h8*>(al_p + kb);
    #pragma unroll
    for (int cg = 0; cg < 4; ++cg) {
      h8 bh = *reinterpret_cast<const h8*>(Hhi + (size_t)lb[cg] * DD + kg * 8 + kb);
      h8 bl = *reinterpret_cast<const h8*>(Hlo + (size_t)lb[cg] * DD + kg * 8 + kb);
      acc1[cg] = MFMA16(ah, bh, acc1[cg]);
      acc2[cg] = MFMA16(ah, bl, acc2[cg]);
      acc2[cg] = MFMA16(al, bh, acc2[cg]);
    }
  }
  __syncthreads();
  int rloc = wv * 16 + kg * 4;
  float nrv[4];
  #pragma unroll
  for (int i = 0; i < 4; ++i) {
    int r = r0 + rloc + i;
    nrv[i] = norms[NL + (r < NL ? r : NL - 1)];
  }
  #pragma unroll
  for (int cg = 0; cg < 4; ++cg) {
    int lloc = cg * 16 + fr;
    int l = n0 + lloc;
    float nlv = norms[l < NL ? l : NL - 1];
    #pragma unroll
    for (int i = 0; i < 4; ++i) {
      int r = r0 + rloc + i;
      float dot = acc1[cg][i] + acc2[cg][i] * (1.f / 2048.f);
      if (r < NL && l < NL && dot > 0.1f * nrv[i] * nlv)
        atomicOr(&mw[rloc + i][lloc >> 5], 1u << (lloc & 31));
    }
  }
  __syncthreads();
  if (t < 128) {
    int rr = t >> 1, w = t & 1;
    int rg = r0 + rr, wg = blockIdx.y * 2 + w;
    if (rg < NL && wg < WPR) mask[(size_t)rg * WPR + wg] = mw[rr][w];
  }
}

// ---------------------------------------------------------------- build neighbor lists from bitmask (once)
__global__ __launch_bounds__(64) void build_csr(const unsigned* __restrict__ mask,
                                                int* __restrict__ nbr, int* __restrict__ deg) {
  int r = blockIdx.x * 64 + threadIdx.x;
  if (r >= NL) return;
  const unsigned* mr = mask + (size_t)r * WPR;
  int* out = nbr + (size_t)r * MAXDEG;
  int cnt = 0;
  #pragma unroll 7
  for (int w = 0; w < WPR; ++w) {
    unsigned m = mr[w];
    while (m) {
      int bpos = __ffs(m) - 1;
      m &= m - 1;
      if (cnt < MAXDEG) out[cnt] = w * 32 + bpos;
      ++cnt;
    }
  }
  deg[r] = cnt < MAXDEG ? cnt : MAXDEG;
}

// ---------------------------------------------------------------- fused sparse bipartite attention
__global__ __launch_bounds__(768) void bip_fused(const float* __restrict__ z, const float* __restrict__ el,
                                                 const float* __restrict__ er, const int* __restrict__ nbr,
                                                 const int* __restrict__ deg, const float* __restrict__ bias,
                                                 float* __restrict__ hout, int do_elu) {
  int r = blockIdx.x;
  int R = NL + r;
  int t = threadIdx.x;
  int dg = deg[r];
  __shared__ int nb_s[MAXDEG];
  __shared__ float wbuf[MAXDEG * NH];
  __shared__ float den_s[NH], wself_s[NH];
  if (t < dg) nb_s[t] = nbr[(size_t)r * MAXDEG + t];
  __syncthreads();
  if (t < dg * NH) {
    int j = t / NH, h2 = t - j * NH;
    wbuf[t] = el[(size_t)nb_s[j] * NH + h2];
  }
  __syncthreads();
  if (t < NH) {
    float er_r = er[(size_t)R * NH + t];
    float s = leaky(el[(size_t)R * NH + t] + er_r);
    float mx = s;
    for (int j = 0; j < dg; ++j) mx = fmaxf(mx, leaky(wbuf[j * NH + t] + er_r));
    float den = 0.f;
    for (int j = 0; j < dg; ++j) {
      float w = expf(leaky(wbuf[j * NH + t] + er_r) - mx);
      wbuf[j * NH + t] = w;
      den += w;
    }
    float ws = expf(s - mx);
    den_s[t] = den + ws;
    wself_s[t] = ws;
  }
  __syncthreads();
  int h2 = t >> 6;
  float acc = wself_s[h2] * z[(size_t)R * DD + t];
  for (int j = 0; j < dg; ++j)
    acc = fmaf(wbuf[j * NH + h2], z[(size_t)nb_s[j] * DD + t], acc);
  float o = acc / den_s[h2] + bias[t];
  if (do_elu) o = o > 0.f ? o : expm1f(o);
  hout[(size_t)R * DD + t] = o;
}

// ---------------------------------------------------------------- pool attention, one (group, head) per wave
__global__ __launch_bounds__(64) void pool_attn2(const float* __restrict__ z, const float* __restrict__ el,
                                                 const float* __restrict__ er, const float* __restrict__ bias,
                                                 float* __restrict__ hout, int do_elu) {
  int g = blockIdx.x, h = blockIdx.y;
  int base = g * 196;
  int t = threadIdx.x;
  __shared__ float wb[196];
  float er0 = er[(size_t)base * NH + h];
  float lmax = -INFINITY;
  float lg[4];
  #pragma unroll
  for (int k = 0; k < 4; ++k) {
    int p = t + k * 64;
    if (p < 196) {
      float v = leaky(el[(size_t)(base + p) * NH + h] + er0);
      if (p == 0) v += LOG2F_;
      lg[k] = v; lmax = fmaxf(lmax, v);
    } else lg[k] = -INFINITY;
  }
  #pragma unroll
  for (int o = 32; o; o >>= 1) lmax = fmaxf(lmax, __shfl_xor(lmax, o));
  float den = 0.f;
  #pragma unroll
  for (int k = 0; k < 4; ++k) {
    int p = t + k * 64;
    if (p < 196) { float w = expf(lg[k] - lmax); wb[p] = w; den += w; }
  }
  #pragma unroll
  for (int o = 32; o; o >>= 1) den += __shfl_xor(den, o);
  __syncthreads();
  float acc = 0.f;
  #pragma unroll 4
  for (int p = 0; p < 196; ++p)
    acc = fmaf(wb[p], z[(size_t)(base + p) * DD + h * DHD + t], acc);
  float o = acc / den + bias[h * DHD + t];
  if (do_elu) o = o > 0.f ? o : expm1f(o);
  hout[(size_t)base * DD + h * DHD + t] = o;
}

// ---------------------------------------------------------------- gather 16 root rows
__global__ void gather_out(const float* __restrict__ h, float* __restrict__ out) {
  int idx = blockIdx.x * 256 + threadIdx.x;
  if (idx >= 16 * DD) return;
  int g = idx / DD, d = idx - g * DD;
  out[idx] = h[(size_t)(g * 196) * DD + d];
}

extern "C" void kernel_launch(void* const* d_in, const int* in_sizes, int n_in,
                              void* d_out, int out_size, void* d_ws, size_t ws_size,
                              hipStream_t stream) {
  const float* l_feat = (const float*)d_in[0];
  const float* r_feat = (const float*)d_in[1];
  const float* W      = (const float*)d_in[2];   // (4, 768, 768)
  const float* a_src  = (const float*)d_in[3];   // (4, 12, 64)
  const float* a_dst  = (const float*)d_in[4];
  const float* b      = (const float*)d_in[5];   // (4, 768)
  float* out = (float*)d_out;

  float* h     = (float*)d_ws;                   // NTOT*DD
  float* z     = h + (size_t)NTOT * DD;          // NTOT*DD
  float* el    = z + (size_t)NTOT * DD;          // NTOT*NH
  float* er    = el + (size_t)NTOT * NH;         // NTOT*NH
  float* norms = er + (size_t)NTOT * NH;         // NTOT
  unsigned* mask = (unsigned*)(norms + NTOT);    // NL*WPR
  int* nbr = (int*)(mask + (size_t)NL * WPR);    // NL*MAXDEG
  int* deg = nbr + (size_t)NL * MAXDEG;          // NL
  _Float16* hhi = (_Float16*)(deg + NL);         // NTOT*DD halves
  _Float16* hlo = hhi + (size_t)NTOT * DD;
  _Float16* Wthi = hlo + (size_t)NTOT * DD;      // 4*DD*DD halves
  _Float16* Wtlo = Wthi + (size_t)4 * DD * DD;

  init_h<<<(NTOT * DD + 255) / 256, 256, 0, stream>>>(l_feat, r_feat, h);
  conv_h<<<(NTOT * DD / 4 + 255) / 256, 256, 0, stream>>>(h, hhi, hlo);
  norms_kernel<<<NTOT, 256, 0, stream>>>(h, norms);
  transp_W<<<dim3(24, 24, 4), 256, 0, stream>>>(W, Wthi, Wtlo);
  mask_mfma<<<dim3(25, 25), 256, 0, stream>>>(hhi, hlo, norms, mask);
  build_csr<<<(NL + 63) / 64, 64, 0, stream>>>(mask, nbr, deg);

  // ---- 4 bipartite layers
  for (int i = 0; i < 4; ++i) {
    const float* bi = b + (size_t)i * DD;
    int do_elu = (i < 3) ? 1 : 0;
    if (i > 0) conv_h<<<(NTOT * DD / 4 + 255) / 256, 256, 0, stream>>>(h, hhi, hlo);
    gemm_mfma<<<dim3(49, 12), 256, 0, stream>>>(hhi, hlo,
        Wthi + (size_t)i * DD * DD, Wtlo + (size_t)i * DD * DD,
        a_src + (size_t)i * NH * DHD, a_dst + (size_t)i * NH * DHD,
        bi, z, el, er, h, do_elu, 0);
    bip_fused<<<NL, 768, 0, stream>>>(z, el, er, nbr, deg, bi, h, do_elu);
  }

  // ---- 4 pool layers
  for (int i = 0; i < 4; ++i) {
    const float* bi = b + (size_t)i * DD;
    int do_elu = (i < 3) ? 1 : 0;
    conv_h<<<(NTOT * DD / 4 + 255) / 256, 256, 0, stream>>>(h, hhi, hlo);
    gemm_mfma<<<dim3(49, 12), 256, 0, stream>>>(hhi, hlo,
        Wthi + (size_t)i * DD * DD, Wtlo + (size_t)i * DD * DD,
        a_src + (size_t)i * NH * DHD, a_dst + (size_t)i * NH * DHD,
        bi, z, el, er, h, do_elu, 1);
    pool_attn2<<<dim3(16, NH), 64, 0, stream>>>(z, el, er, bi, h, do_elu);
  }

  gather_out<<<(16 * DD + 255) / 256, 256, 0, stream>>>(h, out);
}

// Round 8
// 399.024 us; speedup vs baseline: 2.4609x; 2.4609x over previous
//
#include <hip/hip_runtime.h>
#include <math.h>

// Problem constants
#define NL    1568          // left nodes (B*P)
#define NTOT  3136          // total nodes
#define DD    768           // feature dim
#define NH    12            // heads
#define DHD   64            // head dim
#define WPR   49            // mask words per row (1568/32)
#define MAXDEG 64           // neighbor-list capacity
#define NKSTEP 24           // 768 / 32
#define LOG2F_ 0.69314718055994530942f

typedef _Float16 h8 __attribute__((ext_vector_type(8)));
typedef float f32x4 __attribute__((ext_vector_type(4)));
#define MFMA16(a, b, c) __builtin_amdgcn_mfma_f32_16x16x32_f16(a, b, c, 0, 0, 0)

__device__ __forceinline__ float leaky(float x) { return x > 0.f ? x : 0.2f * x; }

__device__ __forceinline__ void gld16(const _Float16* g, _Float16* l) {
  __builtin_amdgcn_global_load_lds(
      (const __attribute__((address_space(1))) void*)g,
      (__attribute__((address_space(3))) void*)l, 16, 0, 0);
}

// ---------------------------------------------------------------- inputs -> fp16 hi/lo planes
__global__ void conv_init(const float* __restrict__ lf, const float* __restrict__ rf,
                          _Float16* __restrict__ hi, _Float16* __restrict__ lo) {
  int idx = blockIdx.x * 256 + threadIdx.x;
  if (idx >= NTOT * DD / 4) return;
  float4 v = (idx < NL * DD / 4) ? reinterpret_cast<const float4*>(lf)[idx]
                                 : reinterpret_cast<const float4*>(rf)[idx - NL * DD / 4];
  _Float16 a0 = (_Float16)v.x, a1 = (_Float16)v.y, a2 = (_Float16)v.z, a3 = (_Float16)v.w;
  typedef _Float16 h4v __attribute__((ext_vector_type(4)));
  h4v hv = {a0, a1, a2, a3};
  h4v lv = {(_Float16)((v.x - (float)a0) * 2048.f), (_Float16)((v.y - (float)a1) * 2048.f),
            (_Float16)((v.z - (float)a2) * 2048.f), (_Float16)((v.w - (float)a3) * 2048.f)};
  reinterpret_cast<h4v*>(hi)[idx] = hv;
  reinterpret_cast<h4v*>(lo)[idx] = lv;
}

// ---------------------------------------------------------------- W[i][k][n] -> Wt[i][n][k] hi/lo fp16
__global__ __launch_bounds__(256) void transp_W(const float* __restrict__ W, _Float16* __restrict__ Wthi,
                                                _Float16* __restrict__ Wtlo) {
  __shared__ float tile[32][33];
  int kt = blockIdx.x * 32, nt = blockIdx.y * 32, i = blockIdx.z;
  int tx = threadIdx.x & 31, ty = threadIdx.x >> 5;
  const float* Wp = W + ((size_t)i * DD + kt) * DD + nt;
  #pragma unroll
  for (int p = 0; p < 4; ++p) tile[ty + p * 8][tx] = Wp[(size_t)(ty + p * 8) * DD + tx];
  __syncthreads();
  _Float16* oh = Wthi + ((size_t)i * DD + nt) * DD + kt;
  _Float16* ol = Wtlo + ((size_t)i * DD + nt) * DD + kt;
  #pragma unroll
  for (int p = 0; p < 4; ++p) {
    int nn = ty + p * 8;
    float v = tile[tx][nn];
    _Float16 vh = (_Float16)v;
    oh[(size_t)nn * DD + tx] = vh;
    ol[(size_t)nn * DD + tx] = (_Float16)((v - (float)vh) * 2048.f);
  }
}

// ---------------------------------------------------------------- row norms from raw inputs
__global__ __launch_bounds__(256) void norms2(const float* __restrict__ lf, const float* __restrict__ rf,
                                              float* __restrict__ norms) {
  int n = blockIdx.x;
  const float* src = (n < NL) ? lf + (size_t)n * DD : rf + (size_t)(n - NL) * DD;
  __shared__ float red[256];
  float s = 0.f;
  for (int d = threadIdx.x; d < DD; d += 256) {
    float v = src[d];
    s = fmaf(v, v, s);
  }
  red[threadIdx.x] = s;
  __syncthreads();
  for (int o = 128; o > 0; o >>= 1) {
    if (threadIdx.x < o) red[threadIdx.x] += red[threadIdx.x + o];
    __syncthreads();
  }
  if (threadIdx.x == 0) norms[n] = sqrtf(red[0]);
}

// ---------------------------------------------------------------- LDS-staged MFMA GEMM + fused epilogue
// 1D grid 588 (XCD-swizzled -> bx 0..48 row-tile, by 0..11 head). 256 thr = 4 waves x 16 rows.
// LDS tiles 64x32 fp16, kq pre-swizzled (kq' = kq ^ ((row>>1)&3)) for conflict-free b128 reads.
// IN planes (Ahi/Alo) and OUT planes (ohhi/ohlo) are DISTINCT buffers (ping-pong) - no in-place race.
__global__ __launch_bounds__(256) void gemm_mfma(const _Float16* __restrict__ Ahi, const _Float16* __restrict__ Alo,
                                                 const _Float16* __restrict__ Bhi, const _Float16* __restrict__ Blo,
                                                 const float* __restrict__ a_s, const float* __restrict__ a_d,
                                                 const float* __restrict__ bias, float* __restrict__ C,
                                                 float* __restrict__ el, float* __restrict__ er,
                                                 _Float16* __restrict__ ohhi, _Float16* __restrict__ ohlo,
                                                 int do_elu, int mode) {
  __shared__ _Float16 sm[2][4][2048];   // [buf][Ahi,Alo,Bhi,Blo][64*32]
  int t = threadIdx.x;
  // bijective XCD swizzle: 588 = 4*74 + 4*73
  int xcd = blockIdx.x & 7, pos = blockIdx.x >> 3;
  int orig = (xcd < 4 ? xcd * 74 : 4 * 74 + (xcd - 4) * 73) + pos;
  int bx = orig / 12, by = orig % 12;
  int m0 = bx * 64, n0 = by * 64;

  // staging source offsets (thread t stages LDS slot t*16B = (row t>>2, kq' t&3))
  int rl = t >> 2;
  int kq_src = (t & 3) ^ ((t >> 3) & 3);
  size_t aoff = (size_t)(m0 + rl) * DD + kq_src * 8;
  size_t boff = (size_t)(n0 + rl) * DD + kq_src * 8;
  const _Float16* pAhi = Ahi + aoff;
  const _Float16* pAlo = Alo + aoff;
  const _Float16* pBhi = Bhi + boff;
  const _Float16* pBlo = Blo + boff;
  int ch = (t >> 6) * 512;             // wave-uniform LDS chunk (halves)

  int ln = t & 63, wv = t >> 6;
  int fr = ln & 15, kg = ln >> 4;
  int kq8 = (kg ^ ((fr >> 1) & 3)) * 8;  // swizzled fragment k-offset (halves)
  int aRead = (wv * 16 + fr) * 32 + kq8;

  f32x4 zero = {0.f, 0.f, 0.f, 0.f};
  f32x4 acc1[4], acc2[4];
  #pragma unroll
  for (int cg = 0; cg < 4; ++cg) { acc1[cg] = zero; acc2[cg] = zero; }

  gld16(pAhi, &sm[0][0][ch]);
  gld16(pAlo, &sm[0][1][ch]);
  gld16(pBhi, &sm[0][2][ch]);
  gld16(pBlo, &sm[0][3][ch]);
  __syncthreads();

  for (int step = 0; step < NKSTEP; ++step) {
    int buf = step & 1;
    if (step < NKSTEP - 1) {
      int kb = (step + 1) * 32;
      gld16(pAhi + kb, &sm[buf ^ 1][0][ch]);
      gld16(pAlo + kb, &sm[buf ^ 1][1][ch]);
      gld16(pBhi + kb, &sm[buf ^ 1][2][ch]);
      gld16(pBlo + kb, &sm[buf ^ 1][3][ch]);
    }
    h8 ah = *reinterpret_cast<const h8*>(&sm[buf][0][aRead]);
    h8 al = *reinterpret_cast<const h8*>(&sm[buf][1][aRead]);
    #pragma unroll
    for (int cg = 0; cg < 4; ++cg) {
      int bRead = (cg * 16 + fr) * 32 + kq8;
      h8 bh = *reinterpret_cast<const h8*>(&sm[buf][2][bRead]);
      h8 bl = *reinterpret_cast<const h8*>(&sm[buf][3][bRead]);
      acc1[cg] = MFMA16(ah, bh, acc1[cg]);
      acc2[cg] = MFMA16(ah, bl, acc2[cg]);
      acc2[cg] = MFMA16(al, bh, acc2[cg]);
    }
    __syncthreads();
  }

  int head = by;
  int orow = m0 + wv * 16 + kg * 4;
  float zv[4][4];
  #pragma unroll
  for (int cg = 0; cg < 4; ++cg)
    #pragma unroll
    for (int i = 0; i < 4; ++i) zv[cg][i] = acc1[cg][i] + acc2[cg][i] * (1.f / 2048.f);
  // z + fused h-plane write (to OUT buffers)
  #pragma unroll
  for (int i = 0; i < 4; ++i) {
    int r = orow + i;
    bool wh = (mode == 0) ? (r < NL) : (r % 196 != 0);
    #pragma unroll
    for (int cg = 0; cg < 4; ++cg) {
      int c = n0 + cg * 16 + fr;
      float z = zv[cg][i];
      C[(size_t)r * DD + c] = z;
      if (wh) {
        float o = z + bias[c];
        if (do_elu) o = o > 0.f ? o : expm1f(o);
        _Float16 oh = (_Float16)o;
        ohhi[(size_t)r * DD + c] = oh;
        ohlo[(size_t)r * DD + c] = (_Float16)((o - (float)oh) * 2048.f);
      }
    }
  }
  // fused el/er (this block owns head == by)
  float asv[4], adv[4];
  #pragma unroll
  for (int cg = 0; cg < 4; ++cg) {
    asv[cg] = a_s[head * DHD + cg * 16 + fr];
    adv[cg] = a_d[head * DHD + cg * 16 + fr];
  }
  #pragma unroll
  for (int i = 0; i < 4; ++i) {
    float s1 = 0.f, s2 = 0.f;
    #pragma unroll
    for (int cg = 0; cg < 4; ++cg) {
      s1 = fmaf(zv[cg][i], asv[cg], s1);
      s2 = fmaf(zv[cg][i], adv[cg], s2);
    }
    #pragma unroll
    for (int o = 1; o < 16; o <<= 1) {
      s1 += __shfl_xor(s1, o);
      s2 += __shfl_xor(s2, o);
    }
    if (fr == 0) {
      el[(size_t)(orow + i) * NH + head] = s1;
      er[(size_t)(orow + i) * NH + head] = s2;
    }
  }
}

// ---------------------------------------------------------------- mask via LDS-staged MFMA (NT)
__global__ __launch_bounds__(256) void mask_mfma(const _Float16* __restrict__ Hhi, const _Float16* __restrict__ Hlo,
                                                 const float* __restrict__ norms, unsigned* __restrict__ mask) {
  __shared__ _Float16 sm[2][4][2048];
  __shared__ unsigned mw[64][2];
  int t = threadIdx.x;
  int r0 = blockIdx.x * 64, l0 = blockIdx.y * 64;

  int rl = t >> 2;
  int kq_src = (t & 3) ^ ((t >> 3) & 3);
  int ra = r0 + rl; if (ra >= NL) ra = NL - 1;
  int la = l0 + rl; if (la >= NL) la = NL - 1;
  size_t aoff = (size_t)(NL + ra) * DD + kq_src * 8;
  size_t boff = (size_t)la * DD + kq_src * 8;
  const _Float16* pAhi = Hhi + aoff;
  const _Float16* pAlo = Hlo + aoff;
  const _Float16* pBhi = Hhi + boff;
  const _Float16* pBlo = Hlo + boff;
  int ch = (t >> 6) * 512;

  int ln = t & 63, wv = t >> 6;
  int fr = ln & 15, kg = ln >> 4;
  int kq8 = (kg ^ ((fr >> 1) & 3)) * 8;
  int aRead = (wv * 16 + fr) * 32 + kq8;

  f32x4 zero = {0.f, 0.f, 0.f, 0.f};
  f32x4 acc1[4], acc2[4];
  #pragma unroll
  for (int cg = 0; cg < 4; ++cg) { acc1[cg] = zero; acc2[cg] = zero; }
  if (t < 128) mw[t >> 1][t & 1] = 0u;

  gld16(pAhi, &sm[0][0][ch]);
  gld16(pAlo, &sm[0][1][ch]);
  gld16(pBhi, &sm[0][2][ch]);
  gld16(pBlo, &sm[0][3][ch]);
  __syncthreads();

  for (int step = 0; step < NKSTEP; ++step) {
    int buf = step & 1;
    if (step < NKSTEP - 1) {
      int kb = (step + 1) * 32;
      gld16(pAhi + kb, &sm[buf ^ 1][0][ch]);
      gld16(pAlo + kb, &sm[buf ^ 1][1][ch]);
      gld16(pBhi + kb, &sm[buf ^ 1][2][ch]);
      gld16(pBlo + kb, &sm[buf ^ 1][3][ch]);
    }
    h8 ah = *reinterpret_cast<const h8*>(&sm[buf][0][aRead]);
    h8 al = *reinterpret_cast<const h8*>(&sm[buf][1][aRead]);
    #pragma unroll
    for (int cg = 0; cg < 4; ++cg) {
      int bRead = (cg * 16 + fr) * 32 + kq8;
      h8 bh = *reinterpret_cast<const h8*>(&sm[buf][2][bRead]);
      h8 bl = *reinterpret_cast<const h8*>(&sm[buf][3][bRead]);
      acc1[cg] = MFMA16(ah, bh, acc1[cg]);
      acc2[cg] = MFMA16(ah, bl, acc2[cg]);
      acc2[cg] = MFMA16(al, bh, acc2[cg]);
    }
    __syncthreads();
  }

  int rloc = wv * 16 + kg * 4;
  float nrv[4];
  #pragma unroll
  for (int i = 0; i < 4; ++i) {
    int r = r0 + rloc + i;
    nrv[i] = norms[NL + (r < NL ? r : NL - 1)];
  }
  #pragma unroll
  for (int cg = 0; cg < 4; ++cg) {
    int lloc = cg * 16 + fr;
    int l = l0 + lloc;
    float nlv = norms[l < NL ? l : NL - 1];
    #pragma unroll
    for (int i = 0; i < 4; ++i) {
      int r = r0 + rloc + i;
      float dot = acc1[cg][i] + acc2[cg][i] * (1.f / 2048.f);
      if (r < NL && l < NL && dot > 0.1f * nrv[i] * nlv)
        atomicOr(&mw[rloc + i][lloc >> 5], 1u << (lloc & 31));
    }
  }
  __syncthreads();
  if (t < 128) {
    int rr = t >> 1, w = t & 1;
    int rg = r0 + rr, wg = blockIdx.y * 2 + w;
    if (rg < NL && wg < WPR) mask[(size_t)rg * WPR + wg] = mw[rr][w];
  }
}

// ---------------------------------------------------------------- build neighbor lists from bitmask (once)
__global__ __launch_bounds__(64) void build_csr(const unsigned* __restrict__ mask,
                                                int* __restrict__ nbr, int* __restrict__ deg) {
  int r = blockIdx.x * 64 + threadIdx.x;
  if (r >= NL) return;
  const unsigned* mr = mask + (size_t)r * WPR;
  int* out = nbr + (size_t)r * MAXDEG;
  int cnt = 0;
  #pragma unroll 7
  for (int w = 0; w < WPR; ++w) {
    unsigned m = mr[w];
    while (m) {
      int bpos = __ffs(m) - 1;
      m &= m - 1;
      if (cnt < MAXDEG) out[cnt] = w * 32 + bpos;
      ++cnt;
    }
  }
  deg[r] = cnt < MAXDEG ? cnt : MAXDEG;
}

// ---------------------------------------------------------------- fused sparse bipartite attention
__global__ __launch_bounds__(768) void bip_fused(const float* __restrict__ z, const float* __restrict__ el,
                                                 const float* __restrict__ er, const int* __restrict__ nbr,
                                                 const int* __restrict__ deg, const float* __restrict__ bias,
                                                 _Float16* __restrict__ ohhi, _Float16* __restrict__ ohlo,
                                                 int do_elu) {
  int r = blockIdx.x;
  int R = NL + r;
  int t = threadIdx.x;
  int dg = deg[r];
  __shared__ int nb_s[MAXDEG];
  __shared__ float wbuf[MAXDEG * NH];
  __shared__ float den_s[NH], wself_s[NH];
  if (t < dg) nb_s[t] = nbr[(size_t)r * MAXDEG + t];
  __syncthreads();
  if (t < dg * NH) {
    int j = t / NH, h2 = t - j * NH;
    wbuf[t] = el[(size_t)nb_s[j] * NH + h2];
  }
  __syncthreads();
  if (t < NH) {
    float er_r = er[(size_t)R * NH + t];
    float s = leaky(el[(size_t)R * NH + t] + er_r);
    float mx = s;
    for (int j = 0; j < dg; ++j) mx = fmaxf(mx, leaky(wbuf[j * NH + t] + er_r));
    float den = 0.f;
    for (int j = 0; j < dg; ++j) {
      float w = expf(leaky(wbuf[j * NH + t] + er_r) - mx);
      wbuf[j * NH + t] = w;
      den += w;
    }
    float ws = expf(s - mx);
    den_s[t] = den + ws;
    wself_s[t] = ws;
  }
  __syncthreads();
  int h2 = t >> 6;
  float acc = wself_s[h2] * z[(size_t)R * DD + t];
  for (int j = 0; j < dg; ++j)
    acc = fmaf(wbuf[j * NH + h2], z[(size_t)nb_s[j] * DD + t], acc);
  float o = acc / den_s[h2] + bias[t];
  if (do_elu) o = o > 0.f ? o : expm1f(o);
  _Float16 oh = (_Float16)o;
  ohhi[(size_t)R * DD + t] = oh;
  ohlo[(size_t)R * DD + t] = (_Float16)((o - (float)oh) * 2048.f);
}

// ---------------------------------------------------------------- pool attention, one (group, head) per wave
__global__ __launch_bounds__(64) void pool_attn2(const float* __restrict__ z, const float* __restrict__ el,
                                                 const float* __restrict__ er, const float* __restrict__ bias,
                                                 _Float16* __restrict__ ohhi, _Float16* __restrict__ ohlo,
                                                 float* __restrict__ root_out, int do_elu) {
  int g = blockIdx.x, h = blockIdx.y;
  int base = g * 196;
  int t = threadIdx.x;
  __shared__ float wb[196];
  float er0 = er[(size_t)base * NH + h];
  float lmax = -INFINITY;
  float lg[4];
  #pragma unroll
  for (int k = 0; k < 4; ++k) {
    int p = t + k * 64;
    if (p < 196) {
      float v = leaky(el[(size_t)(base + p) * NH + h] + er0);
      if (p == 0) v += LOG2F_;
      lg[k] = v; lmax = fmaxf(lmax, v);
    } else lg[k] = -INFINITY;
  }
  #pragma unroll
  for (int o = 32; o; o >>= 1) lmax = fmaxf(lmax, __shfl_xor(lmax, o));
  float den = 0.f;
  #pragma unroll
  for (int k = 0; k < 4; ++k) {
    int p = t + k * 64;
    if (p < 196) { float w = expf(lg[k] - lmax); wb[p] = w; den += w; }
  }
  #pragma unroll
  for (int o = 32; o; o >>= 1) den += __shfl_xor(den, o);
  __syncthreads();
  float acc = 0.f;
  #pragma unroll 4
  for (int p = 0; p < 196; ++p)
    acc = fmaf(wb[p], z[(size_t)(base + p) * DD + h * DHD + t], acc);
  float o = acc / den + bias[h * DHD + t];
  if (do_elu) o = o > 0.f ? o : expm1f(o);
  int c = h * DHD + t;
  _Float16 oh = (_Float16)o;
  ohhi[(size_t)base * DD + c] = oh;
  ohlo[(size_t)base * DD + c] = (_Float16)((o - (float)oh) * 2048.f);
  root_out[(size_t)g * DD + c] = o;
}

extern "C" void kernel_launch(void* const* d_in, const int* in_sizes, int n_in,
                              void* d_out, int out_size, void* d_ws, size_t ws_size,
                              hipStream_t stream) {
  const float* l_feat = (const float*)d_in[0];
  const float* r_feat = (const float*)d_in[1];
  const float* W      = (const float*)d_in[2];   // (4, 768, 768)
  const float* a_src  = (const float*)d_in[3];   // (4, 12, 64)
  const float* a_dst  = (const float*)d_in[4];
  const float* b      = (const float*)d_in[5];   // (4, 768)
  float* out = (float*)d_out;

  float* z     = (float*)d_ws;                   // NTOT*DD
  float* el    = z + (size_t)NTOT * DD;          // NTOT*NH
  float* er    = el + (size_t)NTOT * NH;         // NTOT*NH
  float* norms = er + (size_t)NTOT * NH;         // NTOT
  float* hroot = norms + NTOT;                   // 16*DD scratch
  unsigned* mask = (unsigned*)(hroot + 16 * DD); // NL*WPR
  int* nbr = (int*)(mask + (size_t)NL * WPR);    // NL*MAXDEG
  int* deg = nbr + (size_t)NL * MAXDEG;          // NL
  _Float16* hhiA = (_Float16*)(deg + NL);        // NTOT*DD halves (ping)
  _Float16* hloA = hhiA + (size_t)NTOT * DD;
  _Float16* hhiB = hloA + (size_t)NTOT * DD;     // NTOT*DD halves (pong)
  _Float16* hloB = hhiB + (size_t)NTOT * DD;
  _Float16* Wthi = hloB + (size_t)NTOT * DD;     // 4*DD*DD halves
  _Float16* Wtlo = Wthi + (size_t)4 * DD * DD;

  _Float16* hhi[2] = {hhiA, hhiB};
  _Float16* hlo[2] = {hloA, hloB};

  conv_init<<<(NTOT * DD / 4 + 255) / 256, 256, 0, stream>>>(l_feat, r_feat, hhiA, hloA);
  norms2<<<NTOT, 256, 0, stream>>>(l_feat, r_feat, norms);
  transp_W<<<dim3(24, 24, 4), 256, 0, stream>>>(W, Wthi, Wtlo);
  mask_mfma<<<dim3(25, 25), 256, 0, stream>>>(hhiA, hloA, norms, mask);
  build_csr<<<(NL + 63) / 64, 64, 0, stream>>>(mask, nbr, deg);

  // ---- 4 bipartite layers (ping-pong h planes: layer L reads L&1, writes (L+1)&1)
  for (int i = 0; i < 4; ++i) {
    const float* bi = b + (size_t)i * DD;
    int do_elu = (i < 3) ? 1 : 0;
    int ib = i & 1, ob = (i + 1) & 1;
    gemm_mfma<<<588, 256, 0, stream>>>(hhi[ib], hlo[ib],
        Wthi + (size_t)i * DD * DD, Wtlo + (size_t)i * DD * DD,
        a_src + (size_t)i * NH * DHD, a_dst + (size_t)i * NH * DHD,
        bi, z, el, er, hhi[ob], hlo[ob], do_elu, 0);
    bip_fused<<<NL, 768, 0, stream>>>(z, el, er, nbr, deg, bi, hhi[ob], hlo[ob], do_elu);
  }

  // ---- 4 pool layers
  for (int i = 0; i < 4; ++i) {
    const float* bi = b + (size_t)i * DD;
    int do_elu = (i < 3) ? 1 : 0;
    int L = 4 + i;
    int ib = L & 1, ob = (L + 1) & 1;
    gemm_mfma<<<588, 256, 0, stream>>>(hhi[ib], hlo[ib],
        Wthi + (size_t)i * DD * DD, Wtlo + (size_t)i * DD * DD,
        a_src + (size_t)i * NH * DHD, a_dst + (size_t)i * NH * DHD,
        bi, z, el, er, hhi[ob], hlo[ob], do_elu, 1);
    pool_attn2<<<dim3(16, NH), 64, 0, stream>>>(z, el, er, bi, hhi[ob], hlo[ob],
        (i == 3) ? out : hroot, do_elu);
  }
}

// Round 9
// 359.017 us; speedup vs baseline: 2.7351x; 1.1114x over previous
//
#include <hip/hip_runtime.h>
#include <math.h>

// Problem constants
#define NL    1568          // left nodes (B*P)
#define NTOT  3136          // total nodes
#define DD    768           // feature dim
#define NH    12            // heads
#define DHD   64            // head dim
#define WPR   49            // mask words per row (1568/32)
#define MAXDEG 64           // neighbor-list capacity
#define NKSTEP 24           // 768 / 32
#define LOG2F_ 0.69314718055994530942f

typedef _Float16 h8 __attribute__((ext_vector_type(8)));
typedef float f32x4 __attribute__((ext_vector_type(4)));
#define MFMA16(a, b, c) __builtin_amdgcn_mfma_f32_16x16x32_f16(a, b, c, 0, 0, 0)

__device__ __forceinline__ float leaky(float x) { return x > 0.f ? x : 0.2f * x; }

__device__ __forceinline__ void gld16(const _Float16* g, _Float16* l) {
  __builtin_amdgcn_global_load_lds(
      (const __attribute__((address_space(1))) void*)g,
      (__attribute__((address_space(3))) void*)l, 16, 0, 0);
}

// ---------------------------------------------------------------- inputs -> fp16 hi/lo planes + row norms (fused)
// one block per row, 192 threads (row = 192 float4)
__global__ __launch_bounds__(192) void conv_init(const float* __restrict__ lf, const float* __restrict__ rf,
                                                 _Float16* __restrict__ hi, _Float16* __restrict__ lo,
                                                 float* __restrict__ norms) {
  int n = blockIdx.x;
  int t = threadIdx.x;
  const float* src = (n < NL) ? lf + (size_t)n * DD : rf + (size_t)(n - NL) * DD;
  float4 v = reinterpret_cast<const float4*>(src)[t];
  _Float16 a0 = (_Float16)v.x, a1 = (_Float16)v.y, a2 = (_Float16)v.z, a3 = (_Float16)v.w;
  typedef _Float16 h4v __attribute__((ext_vector_type(4)));
  h4v hv = {a0, a1, a2, a3};
  h4v lv = {(_Float16)((v.x - (float)a0) * 2048.f), (_Float16)((v.y - (float)a1) * 2048.f),
            (_Float16)((v.z - (float)a2) * 2048.f), (_Float16)((v.w - (float)a3) * 2048.f)};
  size_t idx = (size_t)n * (DD / 4) + t;
  reinterpret_cast<h4v*>(hi)[idx] = hv;
  reinterpret_cast<h4v*>(lo)[idx] = lv;
  // norm reduce
  float s = v.x * v.x + v.y * v.y + v.z * v.z + v.w * v.w;
  #pragma unroll
  for (int o = 32; o; o >>= 1) s += __shfl_xor(s, o);
  __shared__ float red[3];
  if ((t & 63) == 0) red[t >> 6] = s;
  __syncthreads();
  if (t == 0) norms[n] = sqrtf(red[0] + red[1] + red[2]);
}

// ---------------------------------------------------------------- W[i][k][n] -> Wt[i][n][k] hi/lo fp16
__global__ __launch_bounds__(256) void transp_W(const float* __restrict__ W, _Float16* __restrict__ Wthi,
                                                _Float16* __restrict__ Wtlo) {
  __shared__ float tile[32][33];
  int kt = blockIdx.x * 32, nt = blockIdx.y * 32, i = blockIdx.z;
  int tx = threadIdx.x & 31, ty = threadIdx.x >> 5;
  const float* Wp = W + ((size_t)i * DD + kt) * DD + nt;
  #pragma unroll
  for (int p = 0; p < 4; ++p) tile[ty + p * 8][tx] = Wp[(size_t)(ty + p * 8) * DD + tx];
  __syncthreads();
  _Float16* oh = Wthi + ((size_t)i * DD + nt) * DD + kt;
  _Float16* ol = Wtlo + ((size_t)i * DD + nt) * DD + kt;
  #pragma unroll
  for (int p = 0; p < 4; ++p) {
    int nn = ty + p * 8;
    float v = tile[tx][nn];
    _Float16 vh = (_Float16)v;
    oh[(size_t)nn * DD + tx] = vh;
    ol[(size_t)nn * DD + tx] = (_Float16)((v - (float)vh) * 2048.f);
  }
}

// ---------------------------------------------------------------- LDS-staged MFMA GEMM + fused epilogue
// A-side plain fp16 (hi only); W split hi/lo (2 MFMA per cg). 1D grid 588, XCD-swizzled.
// LDS tiles 64x32 fp16, kq pre-swizzled (kq' = kq ^ ((row>>1)&3)) for conflict-free b128 reads.
__global__ __launch_bounds__(256) void gemm_mfma(const _Float16* __restrict__ Ahi,
                                                 const _Float16* __restrict__ Bhi, const _Float16* __restrict__ Blo,
                                                 const float* __restrict__ a_s, const float* __restrict__ a_d,
                                                 const float* __restrict__ bias, float* __restrict__ C,
                                                 float* __restrict__ el, float* __restrict__ er,
                                                 _Float16* __restrict__ ohhi,
                                                 int do_elu, int mode) {
  __shared__ _Float16 sm[2][3][2048];   // [buf][Ahi,Bhi,Blo][64*32]
  int t = threadIdx.x;
  // bijective XCD swizzle: 588 = 4*74 + 4*73
  int xcd = blockIdx.x & 7, pos = blockIdx.x >> 3;
  int orig = (xcd < 4 ? xcd * 74 : 4 * 74 + (xcd - 4) * 73) + pos;
  int bx = orig / 12, by = orig % 12;
  int m0 = bx * 64, n0 = by * 64;

  int rl = t >> 2;
  int kq_src = (t & 3) ^ ((t >> 3) & 3);
  size_t aoff = (size_t)(m0 + rl) * DD + kq_src * 8;
  size_t boff = (size_t)(n0 + rl) * DD + kq_src * 8;
  const _Float16* pAhi = Ahi + aoff;
  const _Float16* pBhi = Bhi + boff;
  const _Float16* pBlo = Blo + boff;
  int ch = (t >> 6) * 512;             // wave-uniform LDS chunk (halves)

  int ln = t & 63, wv = t >> 6;
  int fr = ln & 15, kg = ln >> 4;
  int kq8 = (kg ^ ((fr >> 1) & 3)) * 8;  // swizzled fragment k-offset (halves)
  int aRead = (wv * 16 + fr) * 32 + kq8;

  f32x4 zero = {0.f, 0.f, 0.f, 0.f};
  f32x4 acc1[4], acc2[4];
  #pragma unroll
  for (int cg = 0; cg < 4; ++cg) { acc1[cg] = zero; acc2[cg] = zero; }

  gld16(pAhi, &sm[0][0][ch]);
  gld16(pBhi, &sm[0][1][ch]);
  gld16(pBlo, &sm[0][2][ch]);
  __syncthreads();

  for (int step = 0; step < NKSTEP; ++step) {
    int buf = step & 1;
    if (step < NKSTEP - 1) {
      int kb = (step + 1) * 32;
      gld16(pAhi + kb, &sm[buf ^ 1][0][ch]);
      gld16(pBhi + kb, &sm[buf ^ 1][1][ch]);
      gld16(pBlo + kb, &sm[buf ^ 1][2][ch]);
    }
    h8 ah = *reinterpret_cast<const h8*>(&sm[buf][0][aRead]);
    #pragma unroll
    for (int cg = 0; cg < 4; ++cg) {
      int bRead = (cg * 16 + fr) * 32 + kq8;
      h8 bh = *reinterpret_cast<const h8*>(&sm[buf][1][bRead]);
      h8 bl = *reinterpret_cast<const h8*>(&sm[buf][2][bRead]);
      acc1[cg] = MFMA16(ah, bh, acc1[cg]);
      acc2[cg] = MFMA16(ah, bl, acc2[cg]);
    }
    __syncthreads();
  }

  int head = by;
  int orow = m0 + wv * 16 + kg * 4;
  float zv[4][4];
  #pragma unroll
  for (int cg = 0; cg < 4; ++cg)
    #pragma unroll
    for (int i = 0; i < 4; ++i) zv[cg][i] = acc1[cg][i] + acc2[cg][i] * (1.f / 2048.f);
  // z + fused h-plane write (to OUT buffer)
  #pragma unroll
  for (int i = 0; i < 4; ++i) {
    int r = orow + i;
    bool wh = (mode == 0) ? (r < NL) : (r % 196 != 0);
    #pragma unroll
    for (int cg = 0; cg < 4; ++cg) {
      int c = n0 + cg * 16 + fr;
      float z = zv[cg][i];
      C[(size_t)r * DD + c] = z;
      if (wh) {
        float o = z + bias[c];
        if (do_elu) o = o > 0.f ? o : expm1f(o);
        ohhi[(size_t)r * DD + c] = (_Float16)o;
      }
    }
  }
  // fused el/er (this block owns head == by)
  float asv[4], adv[4];
  #pragma unroll
  for (int cg = 0; cg < 4; ++cg) {
    asv[cg] = a_s[head * DHD + cg * 16 + fr];
    adv[cg] = a_d[head * DHD + cg * 16 + fr];
  }
  #pragma unroll
  for (int i = 0; i < 4; ++i) {
    float s1 = 0.f, s2 = 0.f;
    #pragma unroll
    for (int cg = 0; cg < 4; ++cg) {
      s1 = fmaf(zv[cg][i], asv[cg], s1);
      s2 = fmaf(zv[cg][i], adv[cg], s2);
    }
    #pragma unroll
    for (int o = 1; o < 16; o <<= 1) {
      s1 += __shfl_xor(s1, o);
      s2 += __shfl_xor(s2, o);
    }
    if (fr == 0) {
      el[(size_t)(orow + i) * NH + head] = s1;
      er[(size_t)(orow + i) * NH + head] = s2;
    }
  }
}

// ---------------------------------------------------------------- mask via LDS-staged MFMA (NT), FULL hi/lo split
// (mask bits must be exact: a flipped bit is a ~0.2-magnitude output change)
__global__ __launch_bounds__(256) void mask_mfma(const _Float16* __restrict__ Hhi, const _Float16* __restrict__ Hlo,
                                                 const float* __restrict__ norms, unsigned* __restrict__ mask) {
  __shared__ _Float16 sm[2][4][2048];
  __shared__ unsigned mw[64][2];
  int t = threadIdx.x;
  int r0 = blockIdx.x * 64, l0 = blockIdx.y * 64;

  int rl = t >> 2;
  int kq_src = (t & 3) ^ ((t >> 3) & 3);
  int ra = r0 + rl; if (ra >= NL) ra = NL - 1;
  int la = l0 + rl; if (la >= NL) la = NL - 1;
  size_t aoff = (size_t)(NL + ra) * DD + kq_src * 8;
  size_t boff = (size_t)la * DD + kq_src * 8;
  const _Float16* pAhi = Hhi + aoff;
  const _Float16* pAlo = Hlo + aoff;
  const _Float16* pBhi = Hhi + boff;
  const _Float16* pBlo = Hlo + boff;
  int ch = (t >> 6) * 512;

  int ln = t & 63, wv = t >> 6;
  int fr = ln & 15, kg = ln >> 4;
  int kq8 = (kg ^ ((fr >> 1) & 3)) * 8;
  int aRead = (wv * 16 + fr) * 32 + kq8;

  f32x4 zero = {0.f, 0.f, 0.f, 0.f};
  f32x4 acc1[4], acc2[4];
  #pragma unroll
  for (int cg = 0; cg < 4; ++cg) { acc1[cg] = zero; acc2[cg] = zero; }
  if (t < 128) mw[t >> 1][t & 1] = 0u;

  gld16(pAhi, &sm[0][0][ch]);
  gld16(pAlo, &sm[0][1][ch]);
  gld16(pBhi, &sm[0][2][ch]);
  gld16(pBlo, &sm[0][3][ch]);
  __syncthreads();

  for (int step = 0; step < NKSTEP; ++step) {
    int buf = step & 1;
    if (step < NKSTEP - 1) {
      int kb = (step + 1) * 32;
      gld16(pAhi + kb, &sm[buf ^ 1][0][ch]);
      gld16(pAlo + kb, &sm[buf ^ 1][1][ch]);
      gld16(pBhi + kb, &sm[buf ^ 1][2][ch]);
      gld16(pBlo + kb, &sm[buf ^ 1][3][ch]);
    }
    h8 ah = *reinterpret_cast<const h8*>(&sm[buf][0][aRead]);
    h8 al = *reinterpret_cast<const h8*>(&sm[buf][1][aRead]);
    #pragma unroll
    for (int cg = 0; cg < 4; ++cg) {
      int bRead = (cg * 16 + fr) * 32 + kq8;
      h8 bh = *reinterpret_cast<const h8*>(&sm[buf][2][bRead]);
      h8 bl = *reinterpret_cast<const h8*>(&sm[buf][3][bRead]);
      acc1[cg] = MFMA16(ah, bh, acc1[cg]);
      acc2[cg] = MFMA16(ah, bl, acc2[cg]);
      acc2[cg] = MFMA16(al, bh, acc2[cg]);
    }
    __syncthreads();
  }

  int rloc = wv * 16 + kg * 4;
  float nrv[4];
  #pragma unroll
  for (int i = 0; i < 4; ++i) {
    int r = r0 + rloc + i;
    nrv[i] = norms[NL + (r < NL ? r : NL - 1)];
  }
  #pragma unroll
  for (int cg = 0; cg < 4; ++cg) {
    int lloc = cg * 16 + fr;
    int l = l0 + lloc;
    float nlv = norms[l < NL ? l : NL - 1];
    #pragma unroll
    for (int i = 0; i < 4; ++i) {
      int r = r0 + rloc + i;
      float dot = acc1[cg][i] + acc2[cg][i] * (1.f / 2048.f);
      if (r < NL && l < NL && dot > 0.1f * nrv[i] * nlv)
        atomicOr(&mw[rloc + i][lloc >> 5], 1u << (lloc & 31));
    }
  }
  __syncthreads();
  if (t < 128) {
    int rr = t >> 1, w = t & 1;
    int rg = r0 + rr, wg = blockIdx.y * 2 + w;
    if (rg < NL && wg < WPR) mask[(size_t)rg * WPR + wg] = mw[rr][w];
  }
}

// ---------------------------------------------------------------- build neighbor lists from bitmask (once)
__global__ __launch_bounds__(64) void build_csr(const unsigned* __restrict__ mask,
                                                int* __restrict__ nbr, int* __restrict__ deg) {
  int r = blockIdx.x * 64 + threadIdx.x;
  if (r >= NL) return;
  const unsigned* mr = mask + (size_t)r * WPR;
  int* out = nbr + (size_t)r * MAXDEG;
  int cnt = 0;
  #pragma unroll 7
  for (int w = 0; w < WPR; ++w) {
    unsigned m = mr[w];
    while (m) {
      int bpos = __ffs(m) - 1;
      m &= m - 1;
      if (cnt < MAXDEG) out[cnt] = w * 32 + bpos;
      ++cnt;
    }
  }
  deg[r] = cnt < MAXDEG ? cnt : MAXDEG;
}

// ---------------------------------------------------------------- fused sparse bipartite attention
__global__ __launch_bounds__(768) void bip_fused(const float* __restrict__ z, const float* __restrict__ el,
                                                 const float* __restrict__ er, const int* __restrict__ nbr,
                                                 const int* __restrict__ deg, const float* __restrict__ bias,
                                                 _Float16* __restrict__ ohhi,
                                                 int do_elu) {
  int r = blockIdx.x;
  int R = NL + r;
  int t = threadIdx.x;
  int dg = deg[r];
  __shared__ int nb_s[MAXDEG];
  __shared__ float wbuf[MAXDEG * NH];
  __shared__ float den_s[NH], wself_s[NH];
  if (t < dg) nb_s[t] = nbr[(size_t)r * MAXDEG + t];
  __syncthreads();
  if (t < dg * NH) {
    int j = t / NH, h2 = t - j * NH;
    wbuf[t] = el[(size_t)nb_s[j] * NH + h2];
  }
  __syncthreads();
  if (t < NH) {
    float er_r = er[(size_t)R * NH + t];
    float s = leaky(el[(size_t)R * NH + t] + er_r);
    float mx = s;
    for (int j = 0; j < dg; ++j) mx = fmaxf(mx, leaky(wbuf[j * NH + t] + er_r));
    float den = 0.f;
    for (int j = 0; j < dg; ++j) {
      float w = expf(leaky(wbuf[j * NH + t] + er_r) - mx);
      wbuf[j * NH + t] = w;
      den += w;
    }
    float ws = expf(s - mx);
    den_s[t] = den + ws;
    wself_s[t] = ws;
  }
  __syncthreads();
  int h2 = t >> 6;
  float acc = wself_s[h2] * z[(size_t)R * DD + t];
  for (int j = 0; j < dg; ++j)
    acc = fmaf(wbuf[j * NH + h2], z[(size_t)nb_s[j] * DD + t], acc);
  float o = acc / den_s[h2] + bias[t];
  if (do_elu) o = o > 0.f ? o : expm1f(o);
  ohhi[(size_t)R * DD + t] = (_Float16)o;
}

// ---------------------------------------------------------------- pool attention, one (group, head) per wave
__global__ __launch_bounds__(64) void pool_attn2(const float* __restrict__ z, const float* __restrict__ el,
                                                 const float* __restrict__ er, const float* __restrict__ bias,
                                                 _Float16* __restrict__ ohhi,
                                                 float* __restrict__ root_out, int do_elu) {
  int g = blockIdx.x, h = blockIdx.y;
  int base = g * 196;
  int t = threadIdx.x;
  __shared__ float wb[196];
  float er0 = er[(size_t)base * NH + h];
  float lmax = -INFINITY;
  float lg[4];
  #pragma unroll
  for (int k = 0; k < 4; ++k) {
    int p = t + k * 64;
    if (p < 196) {
      float v = leaky(el[(size_t)(base + p) * NH + h] + er0);
      if (p == 0) v += LOG2F_;
      lg[k] = v; lmax = fmaxf(lmax, v);
    } else lg[k] = -INFINITY;
  }
  #pragma unroll
  for (int o = 32; o; o >>= 1) lmax = fmaxf(lmax, __shfl_xor(lmax, o));
  float den = 0.f;
  #pragma unroll
  for (int k = 0; k < 4; ++k) {
    int p = t + k * 64;
    if (p < 196) { float w = expf(lg[k] - lmax); wb[p] = w; den += w; }
  }
  #pragma unroll
  for (int o = 32; o; o >>= 1) den += __shfl_xor(den, o);
  __syncthreads();
  float acc = 0.f;
  #pragma unroll 4
  for (int p = 0; p < 196; ++p)
    acc = fmaf(wb[p], z[(size_t)(base + p) * DD + h * DHD + t], acc);
  float o = acc / den + bias[h * DHD + t];
  if (do_elu) o = o > 0.f ? o : expm1f(o);
  int c = h * DHD + t;
  ohhi[(size_t)base * DD + c] = (_Float16)o;
  root_out[(size_t)g * DD + c] = o;
}

extern "C" void kernel_launch(void* const* d_in, const int* in_sizes, int n_in,
                              void* d_out, int out_size, void* d_ws, size_t ws_size,
                              hipStream_t stream) {
  const float* l_feat = (const float*)d_in[0];
  const float* r_feat = (const float*)d_in[1];
  const float* W      = (const float*)d_in[2];   // (4, 768, 768)
  const float* a_src  = (const float*)d_in[3];   // (4, 12, 64)
  const float* a_dst  = (const float*)d_in[4];
  const float* b      = (const float*)d_in[5];   // (4, 768)
  float* out = (float*)d_out;

  float* z     = (float*)d_ws;                   // NTOT*DD
  float* el    = z + (size_t)NTOT * DD;          // NTOT*NH
  float* er    = el + (size_t)NTOT * NH;         // NTOT*NH
  float* norms = er + (size_t)NTOT * NH;         // NTOT
  float* hroot = norms + NTOT;                   // 16*DD scratch
  unsigned* mask = (unsigned*)(hroot + 16 * DD); // NL*WPR
  int* nbr = (int*)(mask + (size_t)NL * WPR);    // NL*MAXDEG
  int* deg = nbr + (size_t)NL * MAXDEG;          // NL
  _Float16* hhiA = (_Float16*)(deg + NL);        // NTOT*DD halves (ping)
  _Float16* hloA = hhiA + (size_t)NTOT * DD;     // layer-0 lo plane (mask only)
  _Float16* hhiB = hloA + (size_t)NTOT * DD;     // NTOT*DD halves (pong)
  _Float16* Wthi = hhiB + (size_t)NTOT * DD;     // 4*DD*DD halves
  _Float16* Wtlo = Wthi + (size_t)4 * DD * DD;

  _Float16* hhi[2] = {hhiA, hhiB};

  conv_init<<<NTOT, 192, 0, stream>>>(l_feat, r_feat, hhiA, hloA, norms);
  transp_W<<<dim3(24, 24, 4), 256, 0, stream>>>(W, Wthi, Wtlo);
  mask_mfma<<<dim3(25, 25), 256, 0, stream>>>(hhiA, hloA, norms, mask);
  build_csr<<<(NL + 63) / 64, 64, 0, stream>>>(mask, nbr, deg);

  // ---- 4 bipartite layers (ping-pong h planes: layer L reads L&1, writes (L+1)&1)
  for (int i = 0; i < 4; ++i) {
    const float* bi = b + (size_t)i * DD;
    int do_elu = (i < 3) ? 1 : 0;
    int ib = i & 1, ob = (i + 1) & 1;
    gemm_mfma<<<588, 256, 0, stream>>>(hhi[ib],
        Wthi + (size_t)i * DD * DD, Wtlo + (size_t)i * DD * DD,
        a_src + (size_t)i * NH * DHD, a_dst + (size_t)i * NH * DHD,
        bi, z, el, er, hhi[ob], do_elu, 0);
    bip_fused<<<NL, 768, 0, stream>>>(z, el, er, nbr, deg, bi, hhi[ob], do_elu);
  }

  // ---- 4 pool layers
  for (int i = 0; i < 4; ++i) {
    const float* bi = b + (size_t)i * DD;
    int do_elu = (i < 3) ? 1 : 0;
    int L = 4 + i;
    int ib = L & 1, ob = (L + 1) & 1;
    gemm_mfma<<<588, 256, 0, stream>>>(hhi[ib],
        Wthi + (size_t)i * DD * DD, Wtlo + (size_t)i * DD * DD,
        a_src + (size_t)i * NH * DHD, a_dst + (size_t)i * NH * DHD,
        bi, z, el, er, hhi[ob], do_elu, 1);
    pool_attn2<<<dim3(16, NH), 64, 0, stream>>>(z, el, er, bi, hhi[ob],
        (i == 3) ? out : hroot, do_elu);
  }
}

// Round 10
// 274.897 us; speedup vs baseline: 3.5720x; 1.3060x over previous
//
#include <hip/hip_runtime.h>
#include <math.h>

// Problem constants
#define NL    1568          // left nodes (B*P)
#define NTOT  3136          // total nodes
#define DD    768           // feature dim
#define NH    12            // heads
#define DHD   64            // head dim
#define WPR   49            // mask words per row (1568/32)
#define MAXDEG 64           // neighbor-list capacity
#define NKSTEP 24           // 768 / 32
#define LOG2F_ 0.69314718055994530942f

typedef _Float16 h8 __attribute__((ext_vector_type(8)));
typedef float f32x4 __attribute__((ext_vector_type(4)));
#define MFMA16(a, b, c) __builtin_amdgcn_mfma_f32_16x16x32_f16(a, b, c, 0, 0, 0)

__device__ __forceinline__ float leaky(float x) { return x > 0.f ? x : 0.2f * x; }

__device__ __forceinline__ void gld16(const _Float16* g, _Float16* l) {
  __builtin_amdgcn_global_load_lds(
      (const __attribute__((address_space(1))) void*)g,
      (__attribute__((address_space(3))) void*)l, 16, 0, 0);
}

// ---------------------------------------------------------------- inputs -> fp16 hi/lo planes + row norms (fused)
// one block per row, 192 threads (row = 192 float4). lo plane used by mask only.
__global__ __launch_bounds__(192) void conv_init(const float* __restrict__ lf, const float* __restrict__ rf,
                                                 _Float16* __restrict__ hi, _Float16* __restrict__ lo,
                                                 float* __restrict__ norms) {
  int n = blockIdx.x;
  int t = threadIdx.x;
  const float* src = (n < NL) ? lf + (size_t)n * DD : rf + (size_t)(n - NL) * DD;
  float4 v = reinterpret_cast<const float4*>(src)[t];
  _Float16 a0 = (_Float16)v.x, a1 = (_Float16)v.y, a2 = (_Float16)v.z, a3 = (_Float16)v.w;
  typedef _Float16 h4v __attribute__((ext_vector_type(4)));
  h4v hv = {a0, a1, a2, a3};
  h4v lv = {(_Float16)((v.x - (float)a0) * 2048.f), (_Float16)((v.y - (float)a1) * 2048.f),
            (_Float16)((v.z - (float)a2) * 2048.f), (_Float16)((v.w - (float)a3) * 2048.f)};
  size_t idx = (size_t)n * (DD / 4) + t;
  reinterpret_cast<h4v*>(hi)[idx] = hv;
  reinterpret_cast<h4v*>(lo)[idx] = lv;
  float s = v.x * v.x + v.y * v.y + v.z * v.z + v.w * v.w;
  #pragma unroll
  for (int o = 32; o; o >>= 1) s += __shfl_xor(s, o);
  __shared__ float red[3];
  if ((t & 63) == 0) red[t >> 6] = s;
  __syncthreads();
  if (t == 0) norms[n] = sqrtf(red[0] + red[1] + red[2]);
}

// ---------------------------------------------------------------- W[i][k][n] -> Wt[i][n][k] fp16 (hi only)
__global__ __launch_bounds__(256) void transp_W(const float* __restrict__ W, _Float16* __restrict__ Wthi) {
  __shared__ float tile[32][33];
  int kt = blockIdx.x * 32, nt = blockIdx.y * 32, i = blockIdx.z;
  int tx = threadIdx.x & 31, ty = threadIdx.x >> 5;
  const float* Wp = W + ((size_t)i * DD + kt) * DD + nt;
  #pragma unroll
  for (int p = 0; p < 4; ++p) tile[ty + p * 8][tx] = Wp[(size_t)(ty + p * 8) * DD + tx];
  __syncthreads();
  _Float16* oh = Wthi + ((size_t)i * DD + nt) * DD + kt;
  #pragma unroll
  for (int p = 0; p < 4; ++p) {
    int nn = ty + p * 8;
    oh[(size_t)nn * DD + tx] = (_Float16)tile[tx][nn];
  }
}

// ---------------------------------------------------------------- LDS-staged MFMA GEMM (pure fp16) + fused epilogue
// 1D grid 588, XCD-swizzled. 256 thr = 4 waves x 16 rows. LDS 64x32 tiles, kq pre-swizzled.
__global__ __launch_bounds__(256) void gemm_mfma(const _Float16* __restrict__ Ahi,
                                                 const _Float16* __restrict__ Bhi,
                                                 const float* __restrict__ a_s, const float* __restrict__ a_d,
                                                 const float* __restrict__ bias, float* __restrict__ C,
                                                 float* __restrict__ el, float* __restrict__ er,
                                                 _Float16* __restrict__ ohhi,
                                                 int do_elu, int mode) {
  __shared__ _Float16 sm[2][2][2048];   // [buf][Ahi,Bhi][64*32]
  int t = threadIdx.x;
  // bijective XCD swizzle: 588 = 4*74 + 4*73
  int xcd = blockIdx.x & 7, pos = blockIdx.x >> 3;
  int orig = (xcd < 4 ? xcd * 74 : 4 * 74 + (xcd - 4) * 73) + pos;
  int bx = orig / 12, by = orig % 12;
  int m0 = bx * 64, n0 = by * 64;

  int rl = t >> 2;
  int kq_src = (t & 3) ^ ((t >> 3) & 3);
  size_t aoff = (size_t)(m0 + rl) * DD + kq_src * 8;
  size_t boff = (size_t)(n0 + rl) * DD + kq_src * 8;
  const _Float16* pAhi = Ahi + aoff;
  const _Float16* pBhi = Bhi + boff;
  int ch = (t >> 6) * 512;             // wave-uniform LDS chunk (halves)

  int ln = t & 63, wv = t >> 6;
  int fr = ln & 15, kg = ln >> 4;
  int kq8 = (kg ^ ((fr >> 1) & 3)) * 8;  // swizzled fragment k-offset (halves)
  int aRead = (wv * 16 + fr) * 32 + kq8;

  f32x4 zero = {0.f, 0.f, 0.f, 0.f};
  f32x4 acc1[4];
  #pragma unroll
  for (int cg = 0; cg < 4; ++cg) acc1[cg] = zero;

  gld16(pAhi, &sm[0][0][ch]);
  gld16(pBhi, &sm[0][1][ch]);
  __syncthreads();

  for (int step = 0; step < NKSTEP; ++step) {
    int buf = step & 1;
    if (step < NKSTEP - 1) {
      int kb = (step + 1) * 32;
      gld16(pAhi + kb, &sm[buf ^ 1][0][ch]);
      gld16(pBhi + kb, &sm[buf ^ 1][1][ch]);
    }
    h8 ah = *reinterpret_cast<const h8*>(&sm[buf][0][aRead]);
    #pragma unroll
    for (int cg = 0; cg < 4; ++cg) {
      int bRead = (cg * 16 + fr) * 32 + kq8;
      h8 bh = *reinterpret_cast<const h8*>(&sm[buf][1][bRead]);
      acc1[cg] = MFMA16(ah, bh, acc1[cg]);
    }
    __syncthreads();
  }

  int head = by;
  int orow = m0 + wv * 16 + kg * 4;
  // z + fused h-plane write
  #pragma unroll
  for (int i = 0; i < 4; ++i) {
    int r = orow + i;
    bool wh = (mode == 0) ? (r < NL) : (r % 196 != 0);
    #pragma unroll
    for (int cg = 0; cg < 4; ++cg) {
      int c = n0 + cg * 16 + fr;
      float z = acc1[cg][i];
      C[(size_t)r * DD + c] = z;
      if (wh) {
        float o = z + bias[c];
        if (do_elu) o = o > 0.f ? o : expm1f(o);
        ohhi[(size_t)r * DD + c] = (_Float16)o;
      }
    }
  }
  // fused el/er (this block owns head == by)
  float asv[4], adv[4];
  #pragma unroll
  for (int cg = 0; cg < 4; ++cg) {
    asv[cg] = a_s[head * DHD + cg * 16 + fr];
    adv[cg] = a_d[head * DHD + cg * 16 + fr];
  }
  #pragma unroll
  for (int i = 0; i < 4; ++i) {
    float s1 = 0.f, s2 = 0.f;
    #pragma unroll
    for (int cg = 0; cg < 4; ++cg) {
      s1 = fmaf(acc1[cg][i], asv[cg], s1);
      s2 = fmaf(acc1[cg][i], adv[cg], s2);
    }
    #pragma unroll
    for (int o = 1; o < 16; o <<= 1) {
      s1 += __shfl_xor(s1, o);
      s2 += __shfl_xor(s2, o);
    }
    if (fr == 0) {
      el[(size_t)(orow + i) * NH + head] = s1;
      er[(size_t)(orow + i) * NH + head] = s2;
    }
  }
}

// ---------------------------------------------------------------- mask via LDS-staged MFMA (NT), FULL hi/lo split
// (mask bits must be exact: a flipped bit is a ~0.2-magnitude output change)
__global__ __launch_bounds__(256) void mask_mfma(const _Float16* __restrict__ Hhi, const _Float16* __restrict__ Hlo,
                                                 const float* __restrict__ norms, unsigned* __restrict__ mask) {
  __shared__ _Float16 sm[2][4][2048];
  __shared__ unsigned mw[64][2];
  int t = threadIdx.x;
  int r0 = blockIdx.x * 64, l0 = blockIdx.y * 64;

  int rl = t >> 2;
  int kq_src = (t & 3) ^ ((t >> 3) & 3);
  int ra = r0 + rl; if (ra >= NL) ra = NL - 1;
  int la = l0 + rl; if (la >= NL) la = NL - 1;
  size_t aoff = (size_t)(NL + ra) * DD + kq_src * 8;
  size_t boff = (size_t)la * DD + kq_src * 8;
  const _Float16* pAhi = Hhi + aoff;
  const _Float16* pAlo = Hlo + aoff;
  const _Float16* pBhi = Hhi + boff;
  const _Float16* pBlo = Hlo + boff;
  int ch = (t >> 6) * 512;

  int ln = t & 63, wv = t >> 6;
  int fr = ln & 15, kg = ln >> 4;
  int kq8 = (kg ^ ((fr >> 1) & 3)) * 8;
  int aRead = (wv * 16 + fr) * 32 + kq8;

  f32x4 zero = {0.f, 0.f, 0.f, 0.f};
  f32x4 acc1[4], acc2[4];
  #pragma unroll
  for (int cg = 0; cg < 4; ++cg) { acc1[cg] = zero; acc2[cg] = zero; }
  if (t < 128) mw[t >> 1][t & 1] = 0u;

  gld16(pAhi, &sm[0][0][ch]);
  gld16(pAlo, &sm[0][1][ch]);
  gld16(pBhi, &sm[0][2][ch]);
  gld16(pBlo, &sm[0][3][ch]);
  __syncthreads();

  for (int step = 0; step < NKSTEP; ++step) {
    int buf = step & 1;
    if (step < NKSTEP - 1) {
      int kb = (step + 1) * 32;
      gld16(pAhi + kb, &sm[buf ^ 1][0][ch]);
      gld16(pAlo + kb, &sm[buf ^ 1][1][ch]);
      gld16(pBhi + kb, &sm[buf ^ 1][2][ch]);
      gld16(pBlo + kb, &sm[buf ^ 1][3][ch]);
    }
    h8 ah = *reinterpret_cast<const h8*>(&sm[buf][0][aRead]);
    h8 al = *reinterpret_cast<const h8*>(&sm[buf][1][aRead]);
    #pragma unroll
    for (int cg = 0; cg < 4; ++cg) {
      int bRead = (cg * 16 + fr) * 32 + kq8;
      h8 bh = *reinterpret_cast<const h8*>(&sm[buf][2][bRead]);
      h8 bl = *reinterpret_cast<const h8*>(&sm[buf][3][bRead]);
      acc1[cg] = MFMA16(ah, bh, acc1[cg]);
      acc2[cg] = MFMA16(ah, bl, acc2[cg]);
      acc2[cg] = MFMA16(al, bh, acc2[cg]);
    }
    __syncthreads();
  }

  int rloc = wv * 16 + kg * 4;
  float nrv[4];
  #pragma unroll
  for (int i = 0; i < 4; ++i) {
    int r = r0 + rloc + i;
    nrv[i] = norms[NL + (r < NL ? r : NL - 1)];
  }
  #pragma unroll
  for (int cg = 0; cg < 4; ++cg) {
    int lloc = cg * 16 + fr;
    int l = l0 + lloc;
    float nlv = norms[l < NL ? l : NL - 1];
    #pragma unroll
    for (int i = 0; i < 4; ++i) {
      int r = r0 + rloc + i;
      float dot = acc1[cg][i] + acc2[cg][i] * (1.f / 2048.f);
      if (r < NL && l < NL && dot > 0.1f * nrv[i] * nlv)
        atomicOr(&mw[rloc + i][lloc >> 5], 1u << (lloc & 31));
    }
  }
  __syncthreads();
  if (t < 128) {
    int rr = t >> 1, w = t & 1;
    int rg = r0 + rr, wg = blockIdx.y * 2 + w;
    if (rg < NL && wg < WPR) mask[(size_t)rg * WPR + wg] = mw[rr][w];
  }
}

// ---------------------------------------------------------------- build neighbor lists from bitmask (once)
__global__ __launch_bounds__(64) void build_csr(const unsigned* __restrict__ mask,
                                                int* __restrict__ nbr, int* __restrict__ deg) {
  int r = blockIdx.x * 64 + threadIdx.x;
  if (r >= NL) return;
  const unsigned* mr = mask + (size_t)r * WPR;
  int* out = nbr + (size_t)r * MAXDEG;
  int cnt = 0;
  #pragma unroll 7
  for (int w = 0; w < WPR; ++w) {
    unsigned m = mr[w];
    while (m) {
      int bpos = __ffs(m) - 1;
      m &= m - 1;
      if (cnt < MAXDEG) out[cnt] = w * 32 + bpos;
      ++cnt;
    }
  }
  deg[r] = cnt < MAXDEG ? cnt : MAXDEG;
}

// ---------------------------------------------------------------- fused sparse bipartite attention
__global__ __launch_bounds__(768) void bip_fused(const float* __restrict__ z, const float* __restrict__ el,
                                                 const float* __restrict__ er, const int* __restrict__ nbr,
                                                 const int* __restrict__ deg, const float* __restrict__ bias,
                                                 _Float16* __restrict__ ohhi,
                                                 int do_elu) {
  int r = blockIdx.x;
  int R = NL + r;
  int t = threadIdx.x;
  int dg = deg[r];
  __shared__ int nb_s[MAXDEG];
  __shared__ float wbuf[MAXDEG * NH];
  __shared__ float den_s[NH], wself_s[NH];
  if (t < dg) nb_s[t] = nbr[(size_t)r * MAXDEG + t];
  __syncthreads();
  if (t < dg * NH) {
    int j = t / NH, h2 = t - j * NH;
    wbuf[t] = el[(size_t)nb_s[j] * NH + h2];
  }
  __syncthreads();
  if (t < NH) {
    float er_r = er[(size_t)R * NH + t];
    float s = leaky(el[(size_t)R * NH + t] + er_r);
    float mx = s;
    for (int j = 0; j < dg; ++j) mx = fmaxf(mx, leaky(wbuf[j * NH + t] + er_r));
    float den = 0.f;
    for (int j = 0; j < dg; ++j) {
      float w = expf(leaky(wbuf[j * NH + t] + er_r) - mx);
      wbuf[j * NH + t] = w;
      den += w;
    }
    float ws = expf(s - mx);
    den_s[t] = den + ws;
    wself_s[t] = ws;
  }
  __syncthreads();
  int h2 = t >> 6;
  float acc = wself_s[h2] * z[(size_t)R * DD + t];
  for (int j = 0; j < dg; ++j)
    acc = fmaf(wbuf[j * NH + h2], z[(size_t)nb_s[j] * DD + t], acc);
  float o = acc / den_s[h2] + bias[t];
  if (do_elu) o = o > 0.f ? o : expm1f(o);
  ohhi[(size_t)R * DD + t] = (_Float16)o;
}

// ---------------------------------------------------------------- pool attention, (group, head) per block, 4 waves
__global__ __launch_bounds__(256) void pool_attn2(const float* __restrict__ z, const float* __restrict__ el,
                                                  const float* __restrict__ er, const float* __restrict__ bias,
                                                  _Float16* __restrict__ ohhi,
                                                  float* __restrict__ root_out, int do_elu) {
  int g = blockIdx.x, h = blockIdx.y;
  int base = g * 196;
  int t = threadIdx.x;
  int w = t >> 6, d = t & 63;
  __shared__ float wb[196];
  __shared__ float red[4];
  __shared__ float accP[4][64];
  float er0 = er[(size_t)base * NH + h];
  // logits on threads 0..195
  float lg = -INFINITY;
  if (t < 196) {
    lg = leaky(el[(size_t)(base + t) * NH + h] + er0);
    if (t == 0) lg += LOG2F_;
  }
  float m = lg;
  #pragma unroll
  for (int o = 32; o; o >>= 1) m = fmaxf(m, __shfl_xor(m, o));
  if ((t & 63) == 0) red[w] = m;
  __syncthreads();
  float mx = fmaxf(fmaxf(red[0], red[1]), fmaxf(red[2], red[3]));
  float wgt = (t < 196) ? expf(lg - mx) : 0.f;
  if (t < 196) wb[t] = wgt;
  float dn = wgt;
  #pragma unroll
  for (int o = 32; o; o >>= 1) dn += __shfl_xor(dn, o);
  __syncthreads();               // wb visible; red(max) fully consumed
  if ((t & 63) == 0) red[w] = dn;
  __syncthreads();
  float den = red[0] + red[1] + red[2] + red[3];
  // each wave sums its 49-row slice
  float acc = 0.f;
  int p0 = w * 49;
  #pragma unroll 7
  for (int p = p0; p < p0 + 49; ++p)
    acc = fmaf(wb[p], z[(size_t)(base + p) * DD + h * DHD + d], acc);
  accP[w][d] = acc;
  __syncthreads();
  if (w == 0) {
    float o = (accP[0][d] + accP[1][d] + accP[2][d] + accP[3][d]) / den + bias[h * DHD + d];
    if (do_elu) o = o > 0.f ? o : expm1f(o);
    int c = h * DHD + d;
    ohhi[(size_t)base * DD + c] = (_Float16)o;
    root_out[(size_t)g * DD + c] = o;
  }
}

extern "C" void kernel_launch(void* const* d_in, const int* in_sizes, int n_in,
                              void* d_out, int out_size, void* d_ws, size_t ws_size,
                              hipStream_t stream) {
  const float* l_feat = (const float*)d_in[0];
  const float* r_feat = (const float*)d_in[1];
  const float* W      = (const float*)d_in[2];   // (4, 768, 768)
  const float* a_src  = (const float*)d_in[3];   // (4, 12, 64)
  const float* a_dst  = (const float*)d_in[4];
  const float* b      = (const float*)d_in[5];   // (4, 768)
  float* out = (float*)d_out;

  float* z     = (float*)d_ws;                   // NTOT*DD
  float* el    = z + (size_t)NTOT * DD;          // NTOT*NH
  float* er    = el + (size_t)NTOT * NH;         // NTOT*NH
  float* norms = er + (size_t)NTOT * NH;         // NTOT
  float* hroot = norms + NTOT;                   // 16*DD scratch
  unsigned* mask = (unsigned*)(hroot + 16 * DD); // NL*WPR
  int* nbr = (int*)(mask + (size_t)NL * WPR);    // NL*MAXDEG
  int* deg = nbr + (size_t)NL * MAXDEG;          // NL
  _Float16* hhiA = (_Float16*)(deg + NL);        // NTOT*DD halves (ping)
  _Float16* hloA = hhiA + (size_t)NTOT * DD;     // layer-0 lo plane (mask only)
  _Float16* hhiB = hloA + (size_t)NTOT * DD;     // NTOT*DD halves (pong)
  _Float16* Wthi = hhiB + (size_t)NTOT * DD;     // 4*DD*DD halves

  _Float16* hhi[2] = {hhiA, hhiB};

  conv_init<<<NTOT, 192, 0, stream>>>(l_feat, r_feat, hhiA, hloA, norms);
  transp_W<<<dim3(24, 24, 4), 256, 0, stream>>>(W, Wthi);
  mask_mfma<<<dim3(25, 25), 256, 0, stream>>>(hhiA, hloA, norms, mask);
  build_csr<<<(NL + 63) / 64, 64, 0, stream>>>(mask, nbr, deg);

  // ---- 4 bipartite layers (ping-pong h planes: layer L reads L&1, writes (L+1)&1)
  for (int i = 0; i < 4; ++i) {
    const float* bi = b + (size_t)i * DD;
    int do_elu = (i < 3) ? 1 : 0;
    int ib = i & 1, ob = (i + 1) & 1;
    gemm_mfma<<<588, 256, 0, stream>>>(hhi[ib],
        Wthi + (size_t)i * DD * DD,
        a_src + (size_t)i * NH * DHD, a_dst + (size_t)i * NH * DHD,
        bi, z, el, er, hhi[ob], do_elu, 0);
    bip_fused<<<NL, 768, 0, stream>>>(z, el, er, nbr, deg, bi, hhi[ob], do_elu);
  }

  // ---- 4 pool layers
  for (int i = 0; i < 4; ++i) {
    const float* bi = b + (size_t)i * DD;
    int do_elu = (i < 3) ? 1 : 0;
    int L = 4 + i;
    int ib = L & 1, ob = (L + 1) & 1;
    gemm_mfma<<<588, 256, 0, stream>>>(hhi[ib],
        Wthi + (size_t)i * DD * DD,
        a_src + (size_t)i * NH * DHD, a_dst + (size_t)i * NH * DHD,
        bi, z, el, er, hhi[ob], do_elu, 1);
    pool_attn2<<<dim3(16, NH), 256, 0, stream>>>(z, el, er, bi, hhi[ob],
        (i == 3) ? out : hroot, do_elu);
  }
}